// Round 3
// baseline (773.576 us; speedup 1.0000x reference)
//
#include <hip/hip_runtime.h>
#include <cstdint>
#include <cstddef>

typedef __bf16 bf16_t;
typedef __bf16 bf16x8 __attribute__((ext_vector_type(8)));
typedef float f32x4 __attribute__((ext_vector_type(4)));

#define DEVI static __device__ __forceinline__

DEVI f32x4 mfma16(bf16x8 a, bf16x8 b, f32x4 c) {
  return __builtin_amdgcn_mfma_f32_16x16x32_bf16(a, b, c, 0, 0, 0);
}

#define L2E 1.44269504f
#define QSCALE (0.125f * L2E)      // folded into Q projection output
#define MASK_NEG (-60000.0f)       // exp2-domain; exp2(-60000+small) == 0

// ---------------------------------------------------------------------------
// proj_gemm: C = (A[8192,1024](f32) @ W^T + bias) * oscale, out bf16.
// OMODE 1: out[b,h,s,d];  OMODE 2: out[b,h,d,s] (transposed V)
// 128x128 tile, BK=64, 4 waves, mfma 16x16x32 bf16.
// ---------------------------------------------------------------------------
template<int OMODE>
__global__ __launch_bounds__(256)
void proj_gemm(const float* __restrict__ A, const float* __restrict__ W,
               const float* __restrict__ bias, bf16_t* __restrict__ Out,
               float oscale)
{
  __shared__ __align__(16) bf16_t As[128][72];
  __shared__ __align__(16) bf16_t Bs[128][72];
  const int tid  = threadIdx.x;
  const int lane = tid & 63;
  const int wid  = tid >> 6;
  const int g = lane >> 4, c = lane & 15;
  const int mq = (wid >> 1) * 64, nq = (wid & 1) * 64;
  const int srow = tid >> 1, scol = (tid & 1) * 32;
  const int bm = blockIdx.y, bn = blockIdx.x;

  const float* Ap = A + (size_t)(bm * 128 + srow) * 1024 + scol;
  const float* Wp = W + (size_t)(bn * 128 + srow) * 1024 + scol;

  f32x4 acc[4][4] = {};

  for (int kt = 0; kt < 1024; kt += 64) {
    {
      float4 va[8], vb[8];
      #pragma unroll
      for (int i = 0; i < 8; ++i) va[i] = ((const float4*)(Ap + kt))[i];
      #pragma unroll
      for (int i = 0; i < 8; ++i) vb[i] = ((const float4*)(Wp + kt))[i];
      #pragma unroll
      for (int i = 0; i < 4; ++i) {
        bf16x8 pa, pb;
        const float* fa = (const float*)&va[2*i];
        const float* fb = (const float*)&vb[2*i];
        #pragma unroll
        for (int j = 0; j < 8; ++j) { pa[j] = (bf16_t)fa[j]; pb[j] = (bf16_t)fb[j]; }
        *(bf16x8*)&As[srow][scol + 8*i] = pa;
        *(bf16x8*)&Bs[srow][scol + 8*i] = pb;
      }
    }
    __syncthreads();
    #pragma unroll
    for (int kk = 0; kk < 64; kk += 32) {
      bf16x8 af[4], bfv[4];
      #pragma unroll
      for (int i = 0; i < 4; ++i) af[i]  = *(const bf16x8*)&As[mq + i*16 + c][kk + 8*g];
      #pragma unroll
      for (int i = 0; i < 4; ++i) bfv[i] = *(const bf16x8*)&Bs[nq + i*16 + c][kk + 8*g];
      #pragma unroll
      for (int mi = 0; mi < 4; ++mi)
        #pragma unroll
        for (int ni = 0; ni < 4; ++ni)
          acc[mi][ni] = mfma16(af[mi], bfv[ni], acc[mi][ni]);
    }
    __syncthreads();
  }

  #pragma unroll
  for (int ni = 0; ni < 4; ++ni) {
    const int n = bn*128 + nq + ni*16 + c;
    const float bv = bias[n];
    const int h = n >> 6, d = n & 63;
    #pragma unroll
    for (int mi = 0; mi < 4; ++mi) {
      #pragma unroll
      for (int r = 0; r < 4; ++r) {
        const int m = bm*128 + mq + mi*16 + 4*g + r;
        const float v = (acc[mi][ni][r] + bv) * oscale;
        const int bb = m >> 11, s = m & 2047;
        if (OMODE == 1)
          Out[(((size_t)(bb*16 + h))*2048 + s)*64 + d] = (bf16_t)v;
        else
          Out[(((size_t)(bb*16 + h))*64 + d)*2048 + s] = (bf16_t)v;
      }
    }
  }
}

// ---------------------------------------------------------------------------
// out_gemm: split-precision bf16 GEMM (~f32 accurate): Out = A @ W^T + bias
// acc += Ah*Bh + Al*Bh + Ah*Bl
// ---------------------------------------------------------------------------
__global__ __launch_bounds__(256)
void out_gemm(const float* __restrict__ A, const float* __restrict__ W,
              const float* __restrict__ bias, float* __restrict__ Out)
{
  __shared__ __align__(16) bf16_t Ah[128][40];
  __shared__ __align__(16) bf16_t Al[128][40];
  __shared__ __align__(16) bf16_t Bh[128][40];
  __shared__ __align__(16) bf16_t Bl[128][40];
  const int tid  = threadIdx.x;
  const int lane = tid & 63;
  const int wid  = tid >> 6;
  const int g = lane >> 4, c = lane & 15;
  const int mq = (wid >> 1) * 64, nq = (wid & 1) * 64;
  const int srow = tid >> 1, scol = (tid & 1) * 16;
  const int bm = blockIdx.y, bn = blockIdx.x;

  const float* Ap = A + (size_t)(bm * 128 + srow) * 1024 + scol;
  const float* Wp = W + (size_t)(bn * 128 + srow) * 1024 + scol;

  f32x4 acc[4][4] = {};

  for (int kt = 0; kt < 1024; kt += 32) {
    float4 va[4], vb[4];
    #pragma unroll
    for (int i = 0; i < 4; ++i) va[i] = ((const float4*)(Ap + kt))[i];
    #pragma unroll
    for (int i = 0; i < 4; ++i) vb[i] = ((const float4*)(Wp + kt))[i];
    #pragma unroll
    for (int half = 0; half < 2; ++half) {
      bf16x8 ah, al, bh, bl;
      const float* fa = (const float*)&va[2*half];
      const float* fb = (const float*)&vb[2*half];
      #pragma unroll
      for (int j = 0; j < 8; ++j) {
        bf16_t h1 = (bf16_t)fa[j]; ah[j] = h1; al[j] = (bf16_t)(fa[j] - (float)h1);
        bf16_t h2 = (bf16_t)fb[j]; bh[j] = h2; bl[j] = (bf16_t)(fb[j] - (float)h2);
      }
      *(bf16x8*)&Ah[srow][scol + 8*half] = ah;
      *(bf16x8*)&Al[srow][scol + 8*half] = al;
      *(bf16x8*)&Bh[srow][scol + 8*half] = bh;
      *(bf16x8*)&Bl[srow][scol + 8*half] = bl;
    }
    __syncthreads();
    bf16x8 afh[4], afl[4], bfh[4], bfl[4];
    #pragma unroll
    for (int i = 0; i < 4; ++i) {
      afh[i] = *(const bf16x8*)&Ah[mq + i*16 + c][8*g];
      afl[i] = *(const bf16x8*)&Al[mq + i*16 + c][8*g];
      bfh[i] = *(const bf16x8*)&Bh[nq + i*16 + c][8*g];
      bfl[i] = *(const bf16x8*)&Bl[nq + i*16 + c][8*g];
    }
    #pragma unroll
    for (int mi = 0; mi < 4; ++mi)
      #pragma unroll
      for (int ni = 0; ni < 4; ++ni) {
        acc[mi][ni] = mfma16(afh[mi], bfh[ni], acc[mi][ni]);
        acc[mi][ni] = mfma16(afl[mi], bfh[ni], acc[mi][ni]);
        acc[mi][ni] = mfma16(afh[mi], bfl[ni], acc[mi][ni]);
      }
    __syncthreads();
  }

  #pragma unroll
  for (int ni = 0; ni < 4; ++ni) {
    const int n = bn*128 + nq + ni*16 + c;
    const float bv = bias[n];
    #pragma unroll
    for (int mi = 0; mi < 4; ++mi)
      #pragma unroll
      for (int r = 0; r < 4; ++r) {
        const int m = bm*128 + mq + mi*16 + 4*g + r;
        Out[(size_t)m*1024 + n] = acc[mi][ni][r] + bv;
      }
  }
}

// ---------------------------------------------------------------------------
// Flash attention, fixed-max streaming softmax, K-prefetch pipeline.
//  * Q pre-scaled by 0.125*log2e at proj time; relc/mask pre-scaled by log2e
//    -> per-score cost = 1 add + 1 v_exp_f32.
//  * K frags for slab kv+64 issued during slab kv's compute (after V loads,
//    so PV's vmcnt wait does not drain them).
//  * XCD-chunked block swizzle: each XCD owns 8 contiguous heads -> K/V stay
//    in that XCD's L2 (latency + fetch reduction).
// Grid: 2048 x 1. 4 waves/block, wave = 16 q-rows. KT=64.
// ---------------------------------------------------------------------------
__global__ __launch_bounds__(256)
void attn_kernel(const bf16_t* __restrict__ Q, const bf16_t* __restrict__ K,
                 const bf16_t* __restrict__ Vt, const int* __restrict__ mask,
                 const float* __restrict__ rel_emb, float* __restrict__ ctx)
{
  __shared__ float relc[257];      // rel_emb[.,h] * log2e
  __shared__ float maskadd[2048];  // 0 or MASK_NEG (exp2 domain)
  __shared__ __align__(16) bf16_t Plds[4][16][72];

  const int tid  = threadIdx.x;
  const int w    = tid >> 6;
  const int lane = tid & 63;
  const int g = lane >> 4, c = lane & 15;

  const int bid = blockIdx.x;
  const int n   = (bid & 7) * 256 + (bid >> 3);   // XCD-chunked (2048 % 8 == 0)
  const int bh  = n >> 5;
  const int qb  = n & 31;
  const int b = bh >> 4, h = bh & 15;
  const int qw = qb * 64 + w * 16;

  for (int i = tid; i < 257; i += 256)  relc[i] = rel_emb[i * 16 + h] * L2E;
  for (int i = tid; i < 2048; i += 256) maskadd[i] = mask[b * 2048 + i] ? 0.0f : MASK_NEG;
  __syncthreads();

  const bf16_t* Qb = Q  + ((size_t)bh * 2048) * 64;
  const bf16_t* Kb = K  + ((size_t)bh * 2048) * 64;
  const bf16_t* Vb = Vt + ((size_t)bh * 64) * 2048;

  bf16x8 qf[2];
  #pragma unroll
  for (int kk = 0; kk < 2; ++kk)
    qf[kk] = *(const bf16x8*)&Qb[(size_t)(qw + c) * 64 + kk * 32 + 8 * g];

  const float biasLo = relc[0];
  const float biasHi = relc[256];

  f32x4 Of[4] = {};
  float lsum[4] = {0.f, 0.f, 0.f, 0.f};

  bf16x8 kbufA[4][2], kbufB[4][2];

  auto LOADK = [&](bf16x8 (&dst)[4][2], int kv) {
    #pragma unroll
    for (int ni = 0; ni < 4; ++ni)
      #pragma unroll
      for (int kk = 0; kk < 2; ++kk)
        dst[ni][kk] = *(const bf16x8*)&Kb[(size_t)(kv + ni*16 + c) * 64 + kk * 32 + 8 * g];
  };

  auto STEP = [&](const bf16x8 (&kf)[4][2], int kv,
                  bf16x8 (&kpre)[4][2], int kvpre) {
    // ---- QK^T (consumes frags prefetched one phase earlier) ----
    f32x4 sa[4] = {};
    __builtin_amdgcn_s_setprio(1);
    #pragma unroll
    for (int ni = 0; ni < 4; ++ni)
      #pragma unroll
      for (int kk = 0; kk < 2; ++kk)
        sa[ni] = mfma16(qf[kk], kf[ni][kk], sa[ni]);
    __builtin_amdgcn_s_setprio(0);

    // ---- V frag loads for THIS slab (issued before K-prefetch so PV's
    //      vmcnt wait keeps the K-prefetch in flight) ----
    bf16x8 vf[4][2];
    #pragma unroll
    for (int nd = 0; nd < 4; ++nd)
      #pragma unroll
      for (int kk = 0; kk < 2; ++kk)
        vf[nd][kk] = *(const bf16x8*)&Vb[(size_t)(nd*16 + c) * 2048 + kv + kk * 32 + 8 * g];

    // ---- K prefetch for NEXT slab ----
    if (kvpre < 2048) LOADK(kpre, kvpre);

    // ---- exp2(score) (scores pre-scaled; no max subtraction needed) ----
    float p[4][4];
    if (kv >= qw + 143 || kv + 191 <= qw) {
      const float cb = (kv >= qw + 143) ? biasHi : biasLo;
      #pragma unroll
      for (int ni = 0; ni < 4; ++ni) {
        const float ma = maskadd[kv + ni*16 + c] + cb;
        #pragma unroll
        for (int r = 0; r < 4; ++r)
          p[ni][r] = exp2f(sa[ni][r] + ma);
      }
    } else {
      #pragma unroll
      for (int ni = 0; ni < 4; ++ni) {
        const int jj = kv + ni*16 + c;
        const float ma = maskadd[jj];
        #pragma unroll
        for (int r = 0; r < 4; ++r) {
          const int ii = qw + 4*g + r;
          int rr = jj - ii; rr = rr < -128 ? -128 : (rr > 128 ? 128 : rr);
          p[ni][r] = exp2f(sa[ni][r] + relc[rr + 128] + ma);
        }
      }
    }
    #pragma unroll
    for (int r = 0; r < 4; ++r)
      lsum[r] += (p[0][r] + p[1][r]) + (p[2][r] + p[3][r]);

    // ---- P (C-layout) -> LDS -> A-layout frags ----
    #pragma unroll
    for (int ni = 0; ni < 4; ++ni)
      #pragma unroll
      for (int r = 0; r < 4; ++r)
        Plds[w][4*g + r][ni*16 + c] = (bf16_t)p[ni][r];
    asm volatile("s_waitcnt lgkmcnt(0)" ::: "memory");
    __builtin_amdgcn_sched_barrier(0);
    bf16x8 pf[2];
    pf[0] = *(const bf16x8*)&Plds[w][c][8 * g];
    pf[1] = *(const bf16x8*)&Plds[w][c][32 + 8 * g];

    // ---- O += P @ V ----
    __builtin_amdgcn_s_setprio(1);
    #pragma unroll
    for (int nd = 0; nd < 4; ++nd)
      #pragma unroll
      for (int kk = 0; kk < 2; ++kk)
        Of[nd] = mfma16(pf[kk], vf[nd][kk], Of[nd]);
    __builtin_amdgcn_s_setprio(0);
  };

  LOADK(kbufA, 0);
  for (int kv = 0; kv < 2048; kv += 128) {
    STEP(kbufA, kv,       kbufB, kv + 64);
    STEP(kbufB, kv + 64,  kbufA, kv + 128);
  }

  // ---- single deferred row-sum reduction across the 16 c-lanes ----
  #pragma unroll
  for (int r = 0; r < 4; ++r) {
    #pragma unroll
    for (int off = 1; off < 16; off <<= 1)
      lsum[r] += __shfl_xor(lsum[r], off, 64);
  }
  float inv[4];
  #pragma unroll
  for (int r = 0; r < 4; ++r)
    inv[r] = (lsum[r] > 0.0f) ? 1.0f / lsum[r] : 0.0f;   // all-masked row -> 0

  #pragma unroll
  for (int nd = 0; nd < 4; ++nd)
    #pragma unroll
    for (int r = 0; r < 4; ++r) {
      const int s = qw + 4*g + r;
      ctx[((size_t)(b * 2048 + s)) * 1024 + h * 64 + nd*16 + c] = Of[nd][r] * inv[r];
    }
}

// ---------------------------------------------------------------------------
extern "C" void kernel_launch(void* const* d_in, const int* in_sizes, int n_in,
                              void* d_out, int out_size, void* d_ws, size_t ws_size,
                              hipStream_t stream)
{
  const float* q    = (const float*)d_in[0];
  const float* k    = (const float*)d_in[1];
  const float* v    = (const float*)d_in[2];
  const int*   mask = (const int*)  d_in[3];
  const float* Wq   = (const float*)d_in[4];
  const float* bq   = (const float*)d_in[5];
  const float* Wk   = (const float*)d_in[6];
  const float* bk   = (const float*)d_in[7];
  const float* Wv   = (const float*)d_in[8];
  const float* bv   = (const float*)d_in[9];
  const float* Wo   = (const float*)d_in[10];
  const float* bo   = (const float*)d_in[11];
  const float* rel  = (const float*)d_in[12];

  char* wsb = (char*)d_ws;
  bf16_t* Qw = (bf16_t*)(wsb);                        // 16 MB
  bf16_t* Kw = (bf16_t*)(wsb + ((size_t)16 << 20));   // 16 MB
  bf16_t* Vw = (bf16_t*)(wsb + ((size_t)32 << 20));   // 16 MB (transposed)
  float*  Cw = (float*) (wsb + ((size_t)48 << 20));   // 32 MB f32 ctx

  dim3 gg(8, 64), bb(256);
  proj_gemm<1><<<gg, bb, 0, stream>>>(q, Wq, bq, Qw, QSCALE);
  proj_gemm<1><<<gg, bb, 0, stream>>>(k, Wk, bk, Kw, 1.0f);
  proj_gemm<2><<<gg, bb, 0, stream>>>(v, Wv, bv, Vw, 1.0f);
  attn_kernel<<<dim3(2048), bb, 0, stream>>>(Qw, Kw, Vw, mask, rel, Cw);
  out_gemm<<<gg, bb, 0, stream>>>(Cw, Wo, bo, (float*)d_out);
}

// Round 4
// 555.874 us; speedup vs baseline: 1.3916x; 1.3916x over previous
//
#include <hip/hip_runtime.h>
#include <cstdint>
#include <cstddef>

typedef __bf16 bf16_t;
typedef __bf16 bf16x8 __attribute__((ext_vector_type(8)));
typedef float f32x4  __attribute__((ext_vector_type(4)));
typedef float f32x16 __attribute__((ext_vector_type(16)));
typedef int   i32x4  __attribute__((ext_vector_type(4)));

#define DEVI static __device__ __forceinline__

DEVI f32x4 mfma16(bf16x8 a, bf16x8 b, f32x4 c) {
  return __builtin_amdgcn_mfma_f32_16x16x32_bf16(a, b, c, 0, 0, 0);
}
DEVI f32x16 mfma32(bf16x8 a, bf16x8 b, f32x16 c) {
  return __builtin_amdgcn_mfma_f32_32x32x16_bf16(a, b, c, 0, 0, 0);
}
DEVI unsigned cvtpk(float lo, float hi) {
  unsigned d;
  asm("v_cvt_pk_bf16_f32 %0, %1, %2" : "=v"(d) : "v"(lo), "v"(hi));
  return d;
}

#define L2E 1.44269504f
#define QSCALE (0.125f * L2E)      // folded into Q projection output
#define MASK_NEG (-60000.0f)       // exp2-domain; exp2(-60000+small) == 0

// ---------------------------------------------------------------------------
// proj_gemm: C = (A[8192,1024](f32) @ W^T + bias) * oscale, out bf16.
// OMODE 1: out[b,h,s,d];  OMODE 2: out[b,h,d,s] (transposed V)
// ---------------------------------------------------------------------------
template<int OMODE>
__global__ __launch_bounds__(256)
void proj_gemm(const float* __restrict__ A, const float* __restrict__ W,
               const float* __restrict__ bias, bf16_t* __restrict__ Out,
               float oscale)
{
  __shared__ __align__(16) bf16_t As[128][72];
  __shared__ __align__(16) bf16_t Bs[128][72];
  const int tid  = threadIdx.x;
  const int lane = tid & 63;
  const int wid  = tid >> 6;
  const int g = lane >> 4, c = lane & 15;
  const int mq = (wid >> 1) * 64, nq = (wid & 1) * 64;
  const int srow = tid >> 1, scol = (tid & 1) * 32;
  const int bm = blockIdx.y, bn = blockIdx.x;

  const float* Ap = A + (size_t)(bm * 128 + srow) * 1024 + scol;
  const float* Wp = W + (size_t)(bn * 128 + srow) * 1024 + scol;

  f32x4 acc[4][4] = {};

  for (int kt = 0; kt < 1024; kt += 64) {
    {
      float4 va[8], vb[8];
      #pragma unroll
      for (int i = 0; i < 8; ++i) va[i] = ((const float4*)(Ap + kt))[i];
      #pragma unroll
      for (int i = 0; i < 8; ++i) vb[i] = ((const float4*)(Wp + kt))[i];
      #pragma unroll
      for (int i = 0; i < 4; ++i) {
        bf16x8 pa, pb;
        const float* fa = (const float*)&va[2*i];
        const float* fb = (const float*)&vb[2*i];
        #pragma unroll
        for (int j = 0; j < 8; ++j) { pa[j] = (bf16_t)fa[j]; pb[j] = (bf16_t)fb[j]; }
        *(bf16x8*)&As[srow][scol + 8*i] = pa;
        *(bf16x8*)&Bs[srow][scol + 8*i] = pb;
      }
    }
    __syncthreads();
    #pragma unroll
    for (int kk = 0; kk < 64; kk += 32) {
      bf16x8 af[4], bfv[4];
      #pragma unroll
      for (int i = 0; i < 4; ++i) af[i]  = *(const bf16x8*)&As[mq + i*16 + c][kk + 8*g];
      #pragma unroll
      for (int i = 0; i < 4; ++i) bfv[i] = *(const bf16x8*)&Bs[nq + i*16 + c][kk + 8*g];
      #pragma unroll
      for (int mi = 0; mi < 4; ++mi)
        #pragma unroll
        for (int ni = 0; ni < 4; ++ni)
          acc[mi][ni] = mfma16(af[mi], bfv[ni], acc[mi][ni]);
    }
    __syncthreads();
  }

  #pragma unroll
  for (int ni = 0; ni < 4; ++ni) {
    const int n = bn*128 + nq + ni*16 + c;
    const float bv = bias[n];
    const int h = n >> 6, d = n & 63;
    #pragma unroll
    for (int mi = 0; mi < 4; ++mi) {
      #pragma unroll
      for (int r = 0; r < 4; ++r) {
        const int m = bm*128 + mq + mi*16 + 4*g + r;
        const float v = (acc[mi][ni][r] + bv) * oscale;
        const int bb = m >> 11, s = m & 2047;
        if (OMODE == 1)
          Out[(((size_t)(bb*16 + h))*2048 + s)*64 + d] = (bf16_t)v;
        else
          Out[(((size_t)(bb*16 + h))*64 + d)*2048 + s] = (bf16_t)v;
      }
    }
  }
}

// ---------------------------------------------------------------------------
// out_gemm: split-precision bf16 GEMM (~f32 accurate): Out = A @ W^T + bias
// ---------------------------------------------------------------------------
__global__ __launch_bounds__(256)
void out_gemm(const float* __restrict__ A, const float* __restrict__ W,
              const float* __restrict__ bias, float* __restrict__ Out)
{
  __shared__ __align__(16) bf16_t Ah[128][40];
  __shared__ __align__(16) bf16_t Al[128][40];
  __shared__ __align__(16) bf16_t Bh[128][40];
  __shared__ __align__(16) bf16_t Bl[128][40];
  const int tid  = threadIdx.x;
  const int lane = tid & 63;
  const int wid  = tid >> 6;
  const int g = lane >> 4, c = lane & 15;
  const int mq = (wid >> 1) * 64, nq = (wid & 1) * 64;
  const int srow = tid >> 1, scol = (tid & 1) * 16;
  const int bm = blockIdx.y, bn = blockIdx.x;

  const float* Ap = A + (size_t)(bm * 128 + srow) * 1024 + scol;
  const float* Wp = W + (size_t)(bn * 128 + srow) * 1024 + scol;

  f32x4 acc[4][4] = {};

  for (int kt = 0; kt < 1024; kt += 32) {
    float4 va[4], vb[4];
    #pragma unroll
    for (int i = 0; i < 4; ++i) va[i] = ((const float4*)(Ap + kt))[i];
    #pragma unroll
    for (int i = 0; i < 4; ++i) vb[i] = ((const float4*)(Wp + kt))[i];
    #pragma unroll
    for (int half = 0; half < 2; ++half) {
      bf16x8 ah, al, bh, bl;
      const float* fa = (const float*)&va[2*half];
      const float* fb = (const float*)&vb[2*half];
      #pragma unroll
      for (int j = 0; j < 8; ++j) {
        bf16_t h1 = (bf16_t)fa[j]; ah[j] = h1; al[j] = (bf16_t)(fa[j] - (float)h1);
        bf16_t h2 = (bf16_t)fb[j]; bh[j] = h2; bl[j] = (bf16_t)(fb[j] - (float)h2);
      }
      *(bf16x8*)&Ah[srow][scol + 8*half] = ah;
      *(bf16x8*)&Al[srow][scol + 8*half] = al;
      *(bf16x8*)&Bh[srow][scol + 8*half] = bh;
      *(bf16x8*)&Bl[srow][scol + 8*half] = bl;
    }
    __syncthreads();
    bf16x8 afh[4], afl[4], bfh[4], bfl[4];
    #pragma unroll
    for (int i = 0; i < 4; ++i) {
      afh[i] = *(const bf16x8*)&Ah[mq + i*16 + c][8*g];
      afl[i] = *(const bf16x8*)&Al[mq + i*16 + c][8*g];
      bfh[i] = *(const bf16x8*)&Bh[nq + i*16 + c][8*g];
      bfl[i] = *(const bf16x8*)&Bl[nq + i*16 + c][8*g];
    }
    #pragma unroll
    for (int mi = 0; mi < 4; ++mi)
      #pragma unroll
      for (int ni = 0; ni < 4; ++ni) {
        acc[mi][ni] = mfma16(afh[mi], bfh[ni], acc[mi][ni]);
        acc[mi][ni] = mfma16(afl[mi], bfh[ni], acc[mi][ni]);
        acc[mi][ni] = mfma16(afh[mi], bfl[ni], acc[mi][ni]);
      }
    __syncthreads();
  }

  #pragma unroll
  for (int ni = 0; ni < 4; ++ni) {
    const int n = bn*128 + nq + ni*16 + c;
    const float bv = bias[n];
    #pragma unroll
    for (int mi = 0; mi < 4; ++mi)
      #pragma unroll
      for (int r = 0; r < 4; ++r) {
        const int m = bm*128 + mq + mi*16 + 4*g + r;
        Out[(size_t)m*1024 + n] = acc[mi][ni][r] + bv;
      }
  }
}

// ---------------------------------------------------------------------------
// Flash attention: swapped-QK^T 32x32 MFMA, fully in-register softmax.
//  * C = mfma32(A=K, B=Q) -> C[k][q]: col=lane&31=q, row=(reg&3)+8(reg>>2)+4hi=k
//    -> each lane holds 16 P-values of ONE q-row: softmax sum is per-lane.
//  * P -> PV A-frag via v_cvt_pk_bf16_f32 + v_permlane32_swap_b32 (no LDS).
//  * PV B-frag from transposed V (k contiguous). Fixed-max exp2 softmax.
// Grid: 1024 (XCD-chunked). 4 waves/block, wave = 32 q-rows x full D=64.
// ---------------------------------------------------------------------------
__global__ __launch_bounds__(256)
void attn_kernel(const bf16_t* __restrict__ Q, const bf16_t* __restrict__ K,
                 const bf16_t* __restrict__ Vt, const int* __restrict__ mask,
                 const float* __restrict__ rel_emb, float* __restrict__ ctx)
{
  __shared__ float relc[257];      // rel_emb[.,h] * log2e
  __shared__ float maskadd[2048];  // 0 or MASK_NEG (exp2 domain)
  __shared__ float linv[4][32];

  const int tid  = threadIdx.x;
  const int w    = tid >> 6;
  const int lane = tid & 63;
  const int lq   = lane & 31;      // q-col / d-col / kv-row lane index
  const int hi   = lane >> 5;

  const int bid = blockIdx.x;
  const int n   = (bid & 7) * 128 + (bid >> 3);   // XCD-chunked (1024 % 8 == 0)
  const int bh  = n >> 4;
  const int qblk= n & 15;
  const int b = bh >> 4, h = bh & 15;
  const int qw = qblk * 128 + w * 32;             // wave's q-base

  for (int i = tid; i < 257; i += 256)  relc[i] = rel_emb[i * 16 + h] * L2E;
  for (int i = tid; i < 2048; i += 256) maskadd[i] = mask[b * 2048 + i] ? 0.0f : MASK_NEG;
  __syncthreads();

  const bf16_t* Qb = Q  + ((size_t)bh * 2048) * 64;
  const bf16_t* Kb = K  + ((size_t)bh * 2048) * 64;
  const bf16_t* Vb = Vt + ((size_t)bh * 64) * 2048;

  // Q as B-frag (col=q=lq, k-dim=d): hoisted for all 4 d-chunks of 16
  bf16x8 qf[4];
  #pragma unroll
  for (int dc = 0; dc < 4; ++dc)
    qf[dc] = *(const bf16x8*)&Qb[(size_t)(qw + lq) * 64 + dc * 16 + 8 * hi];

  const float biasLo = relc[0];
  const float biasHi = relc[256];

  f32x16 O0 = {}, O1 = {};
  float lsum = 0.0f;

  bf16x8 kfA[4], kfB[4];

  auto LOADK = [&](bf16x8 (&dst)[4], int kv) {
    #pragma unroll
    for (int dc = 0; dc < 4; ++dc)
      dst[dc] = *(const bf16x8*)&Kb[(size_t)(kv + lq) * 64 + dc * 16 + 8 * hi];
  };

  auto STEP = [&](const bf16x8 (&kf)[4], int kv, bf16x8 (&kpre)[4]) {
    // ---- V B-frags for THIS tile (col=d, k contiguous in s) ----
    bf16x8 vf[2][2];
    #pragma unroll
    for (int kc = 0; kc < 2; ++kc)
      #pragma unroll
      for (int db = 0; db < 2; ++db)
        vf[kc][db] = *(const bf16x8*)&Vb[(size_t)(db*32 + lq) * 2048 + kv + kc*16 + 8*hi];
    // ---- K prefetch for NEXT tile (newer than V: PV's V-wait keeps it live) ----
    if (kv + 32 < 2048) LOADK(kpre, kv + 32);

    // ---- S^T = K Q : C[k][q], lane q=lq, rows k per reg pattern ----
    f32x16 sa = {};
    __builtin_amdgcn_s_setprio(1);
    #pragma unroll
    for (int dc = 0; dc < 4; ++dc)
      sa = mfma32(kf[dc], qf[dc], sa);
    __builtin_amdgcn_s_setprio(0);

    // ---- bias + mask + exp2 (fixed-max: scores bounded << exp range) ----
    float p[16];
    const int d0 = kv - qw;
    if (d0 >= 160 || d0 <= -160) {
      const float cb = (d0 >= 160) ? biasHi : biasLo;
      #pragma unroll
      for (int reg = 0; reg < 16; ++reg) {
        const int krow = (reg & 3) + 8 * (reg >> 2) + 4 * hi;
        p[reg] = exp2f(sa[reg] + (cb + maskadd[kv + krow]));
      }
    } else {
      #pragma unroll
      for (int reg = 0; reg < 16; ++reg) {
        const int krow = (reg & 3) + 8 * (reg >> 2) + 4 * hi;
        int rr = kv + krow - (qw + lq);
        rr = rr < -128 ? -128 : (rr > 128 ? 128 : rr);
        p[reg] = exp2f(sa[reg] + relc[rr + 128] + maskadd[kv + krow]);
      }
    }
    #pragma unroll
    for (int reg = 0; reg < 16; ++reg) lsum += p[reg];

    // ---- pack P -> PV A-frags: cvt_pk pairs + permlane32 half-swap ----
    // kc=0 (k 0..15): lane needs k = 8*hi..8*hi+7 for its q.
    unsigned w0 = cvtpk(p[0], p[1]), w1 = cvtpk(p[2], p[3]);
    unsigned w2 = cvtpk(p[4], p[5]), w3 = cvtpk(p[6], p[7]);
    asm volatile("v_permlane32_swap_b32 %0, %1" : "+v"(w0), "+v"(w2));
    asm volatile("v_permlane32_swap_b32 %0, %1" : "+v"(w1), "+v"(w3));
    i32x4 pw0 = { (int)w0, (int)w1, (int)w2, (int)w3 };
    bf16x8 pa0 = __builtin_bit_cast(bf16x8, pw0);
    // kc=1 (k 16..31)
    unsigned w4 = cvtpk(p[8], p[9]),  w5 = cvtpk(p[10], p[11]);
    unsigned w6 = cvtpk(p[12], p[13]), w7 = cvtpk(p[14], p[15]);
    asm volatile("v_permlane32_swap_b32 %0, %1" : "+v"(w4), "+v"(w6));
    asm volatile("v_permlane32_swap_b32 %0, %1" : "+v"(w5), "+v"(w7));
    i32x4 pw1 = { (int)w4, (int)w5, (int)w6, (int)w7 };
    bf16x8 pa1 = __builtin_bit_cast(bf16x8, pw1);

    // ---- O += P @ V ----
    __builtin_amdgcn_s_setprio(1);
    O0 = mfma32(pa0, vf[0][0], O0);
    O1 = mfma32(pa0, vf[0][1], O1);
    O0 = mfma32(pa1, vf[1][0], O0);
    O1 = mfma32(pa1, vf[1][1], O1);
    __builtin_amdgcn_s_setprio(0);
  };

  LOADK(kfA, 0);
  for (int kv = 0; kv < 2048; kv += 64) {
    STEP(kfA, kv,      kfB);
    STEP(kfB, kv + 32, kfA);
  }

  // ---- epilogue: combine half-wave sums; redistribute inv via tiny LDS ----
  lsum += __shfl_xor(lsum, 32);
  if (lane < 32) linv[w][lane] = (lsum > 0.0f) ? 1.0f / lsum : 0.0f;
  asm volatile("s_waitcnt lgkmcnt(0)" ::: "memory");
  __builtin_amdgcn_sched_barrier(0);

  #pragma unroll
  for (int reg = 0; reg < 16; ++reg) {
    const int qrow = (reg & 3) + 8 * (reg >> 2) + 4 * hi;
    const float iv = linv[w][qrow];
    const int s = qw + qrow;
    float* dst = &ctx[((size_t)(b * 2048 + s)) * 1024 + h * 64 + lq];
    dst[0]  = O0[reg] * iv;
    dst[32] = O1[reg] * iv;
  }
}

// ---------------------------------------------------------------------------
extern "C" void kernel_launch(void* const* d_in, const int* in_sizes, int n_in,
                              void* d_out, int out_size, void* d_ws, size_t ws_size,
                              hipStream_t stream)
{
  const float* q    = (const float*)d_in[0];
  const float* k    = (const float*)d_in[1];
  const float* v    = (const float*)d_in[2];
  const int*   mask = (const int*)  d_in[3];
  const float* Wq   = (const float*)d_in[4];
  const float* bq   = (const float*)d_in[5];
  const float* Wk   = (const float*)d_in[6];
  const float* bk   = (const float*)d_in[7];
  const float* Wv   = (const float*)d_in[8];
  const float* bv   = (const float*)d_in[9];
  const float* Wo   = (const float*)d_in[10];
  const float* bo   = (const float*)d_in[11];
  const float* rel  = (const float*)d_in[12];

  char* wsb = (char*)d_ws;
  bf16_t* Qw = (bf16_t*)(wsb);                        // 16 MB
  bf16_t* Kw = (bf16_t*)(wsb + ((size_t)16 << 20));   // 16 MB
  bf16_t* Vw = (bf16_t*)(wsb + ((size_t)32 << 20));   // 16 MB (transposed)
  float*  Cw = (float*) (wsb + ((size_t)48 << 20));   // 32 MB f32 ctx

  dim3 gg(8, 64), bb(256);
  proj_gemm<1><<<gg, bb, 0, stream>>>(q, Wq, bq, Qw, QSCALE);
  proj_gemm<1><<<gg, bb, 0, stream>>>(k, Wk, bk, Kw, 1.0f);
  proj_gemm<2><<<gg, bb, 0, stream>>>(v, Wv, bv, Vw, 1.0f);
  attn_kernel<<<dim3(1024), bb, 0, stream>>>(Qw, Kw, Vw, mask, rel, Cw);
  out_gemm<<<gg, bb, 0, stream>>>(Cw, Wo, bo, (float*)d_out);
}

// Round 5
// 457.957 us; speedup vs baseline: 1.6892x; 1.2138x over previous
//
#include <hip/hip_runtime.h>
#include <cstdint>
#include <cstddef>

typedef __bf16 bf16_t;
typedef __bf16 bf16x8 __attribute__((ext_vector_type(8)));
typedef float f32x4  __attribute__((ext_vector_type(4)));
typedef float f32x16 __attribute__((ext_vector_type(16)));
typedef int   i32x4  __attribute__((ext_vector_type(4)));

#define DEVI static __device__ __forceinline__

DEVI f32x4 mfma16(bf16x8 a, bf16x8 b, f32x4 c) {
  return __builtin_amdgcn_mfma_f32_16x16x32_bf16(a, b, c, 0, 0, 0);
}
DEVI f32x16 mfma32(bf16x8 a, bf16x8 b, f32x16 c) {
  return __builtin_amdgcn_mfma_f32_32x32x16_bf16(a, b, c, 0, 0, 0);
}
DEVI unsigned cvtpk(float lo, float hi) {
  unsigned d;
  asm("v_cvt_pk_bf16_f32 %0, %1, %2" : "=v"(d) : "v"(lo), "v"(hi));
  return d;
}

#define L2E 1.44269504f
#define QSCALE (0.125f * L2E)      // folded into Q projection output
#define MASK_NEG (-60000.0f)       // exp2-domain; exp2(-60000+small) == 0

// ---------------------------------------------------------------------------
// proj_gemm: C = (A[8192,1024](f32) @ W^T + bias) * oscale, out bf16.
// OMODE 1: out[b,h,s,d];  OMODE 2: out[b,h,d,s] (transposed V)
// ---------------------------------------------------------------------------
template<int OMODE>
__global__ __launch_bounds__(256)
void proj_gemm(const float* __restrict__ A, const float* __restrict__ W,
               const float* __restrict__ bias, bf16_t* __restrict__ Out,
               float oscale)
{
  __shared__ __align__(16) bf16_t As[128][72];
  __shared__ __align__(16) bf16_t Bs[128][72];
  const int tid  = threadIdx.x;
  const int lane = tid & 63;
  const int wid  = tid >> 6;
  const int g = lane >> 4, c = lane & 15;
  const int mq = (wid >> 1) * 64, nq = (wid & 1) * 64;
  const int srow = tid >> 1, scol = (tid & 1) * 32;
  const int bm = blockIdx.y, bn = blockIdx.x;

  const float* Ap = A + (size_t)(bm * 128 + srow) * 1024 + scol;
  const float* Wp = W + (size_t)(bn * 128 + srow) * 1024 + scol;

  f32x4 acc[4][4] = {};

  for (int kt = 0; kt < 1024; kt += 64) {
    {
      float4 va[8], vb[8];
      #pragma unroll
      for (int i = 0; i < 8; ++i) va[i] = ((const float4*)(Ap + kt))[i];
      #pragma unroll
      for (int i = 0; i < 8; ++i) vb[i] = ((const float4*)(Wp + kt))[i];
      #pragma unroll
      for (int i = 0; i < 4; ++i) {
        bf16x8 pa, pb;
        const float* fa = (const float*)&va[2*i];
        const float* fb = (const float*)&vb[2*i];
        #pragma unroll
        for (int j = 0; j < 8; ++j) { pa[j] = (bf16_t)fa[j]; pb[j] = (bf16_t)fb[j]; }
        *(bf16x8*)&As[srow][scol + 8*i] = pa;
        *(bf16x8*)&Bs[srow][scol + 8*i] = pb;
      }
    }
    __syncthreads();
    #pragma unroll
    for (int kk = 0; kk < 64; kk += 32) {
      bf16x8 af[4], bfv[4];
      #pragma unroll
      for (int i = 0; i < 4; ++i) af[i]  = *(const bf16x8*)&As[mq + i*16 + c][kk + 8*g];
      #pragma unroll
      for (int i = 0; i < 4; ++i) bfv[i] = *(const bf16x8*)&Bs[nq + i*16 + c][kk + 8*g];
      #pragma unroll
      for (int mi = 0; mi < 4; ++mi)
        #pragma unroll
        for (int ni = 0; ni < 4; ++ni)
          acc[mi][ni] = mfma16(af[mi], bfv[ni], acc[mi][ni]);
    }
    __syncthreads();
  }

  #pragma unroll
  for (int ni = 0; ni < 4; ++ni) {
    const int n = bn*128 + nq + ni*16 + c;
    const float bv = bias[n];
    const int h = n >> 6, d = n & 63;
    #pragma unroll
    for (int mi = 0; mi < 4; ++mi) {
      #pragma unroll
      for (int r = 0; r < 4; ++r) {
        const int m = bm*128 + mq + mi*16 + 4*g + r;
        const float v = (acc[mi][ni][r] + bv) * oscale;
        const int bb = m >> 11, s = m & 2047;
        if (OMODE == 1)
          Out[(((size_t)(bb*16 + h))*2048 + s)*64 + d] = (bf16_t)v;
        else
          Out[(((size_t)(bb*16 + h))*64 + d)*2048 + s] = (bf16_t)v;
      }
    }
  }
}

// ---------------------------------------------------------------------------
// out_gemm: split-precision bf16 GEMM (~f32 accurate): Out = A @ W^T + bias
// ---------------------------------------------------------------------------
__global__ __launch_bounds__(256)
void out_gemm(const float* __restrict__ A, const float* __restrict__ W,
              const float* __restrict__ bias, float* __restrict__ Out)
{
  __shared__ __align__(16) bf16_t Ah[128][40];
  __shared__ __align__(16) bf16_t Al[128][40];
  __shared__ __align__(16) bf16_t Bh[128][40];
  __shared__ __align__(16) bf16_t Bl[128][40];
  const int tid  = threadIdx.x;
  const int lane = tid & 63;
  const int wid  = tid >> 6;
  const int g = lane >> 4, c = lane & 15;
  const int mq = (wid >> 1) * 64, nq = (wid & 1) * 64;
  const int srow = tid >> 1, scol = (tid & 1) * 16;
  const int bm = blockIdx.y, bn = blockIdx.x;

  const float* Ap = A + (size_t)(bm * 128 + srow) * 1024 + scol;
  const float* Wp = W + (size_t)(bn * 128 + srow) * 1024 + scol;

  f32x4 acc[4][4] = {};

  for (int kt = 0; kt < 1024; kt += 32) {
    float4 va[4], vb[4];
    #pragma unroll
    for (int i = 0; i < 4; ++i) va[i] = ((const float4*)(Ap + kt))[i];
    #pragma unroll
    for (int i = 0; i < 4; ++i) vb[i] = ((const float4*)(Wp + kt))[i];
    #pragma unroll
    for (int half = 0; half < 2; ++half) {
      bf16x8 ah, al, bh, bl;
      const float* fa = (const float*)&va[2*half];
      const float* fb = (const float*)&vb[2*half];
      #pragma unroll
      for (int j = 0; j < 8; ++j) {
        bf16_t h1 = (bf16_t)fa[j]; ah[j] = h1; al[j] = (bf16_t)(fa[j] - (float)h1);
        bf16_t h2 = (bf16_t)fb[j]; bh[j] = h2; bl[j] = (bf16_t)(fb[j] - (float)h2);
      }
      *(bf16x8*)&Ah[srow][scol + 8*half] = ah;
      *(bf16x8*)&Al[srow][scol + 8*half] = al;
      *(bf16x8*)&Bh[srow][scol + 8*half] = bh;
      *(bf16x8*)&Bl[srow][scol + 8*half] = bl;
    }
    __syncthreads();
    bf16x8 afh[4], afl[4], bfh[4], bfl[4];
    #pragma unroll
    for (int i = 0; i < 4; ++i) {
      afh[i] = *(const bf16x8*)&Ah[mq + i*16 + c][8*g];
      afl[i] = *(const bf16x8*)&Al[mq + i*16 + c][8*g];
      bfh[i] = *(const bf16x8*)&Bh[nq + i*16 + c][8*g];
      bfl[i] = *(const bf16x8*)&Bl[nq + i*16 + c][8*g];
    }
    #pragma unroll
    for (int mi = 0; mi < 4; ++mi)
      #pragma unroll
      for (int ni = 0; ni < 4; ++ni) {
        acc[mi][ni] = mfma16(afh[mi], bfh[ni], acc[mi][ni]);
        acc[mi][ni] = mfma16(afl[mi], bfh[ni], acc[mi][ni]);
        acc[mi][ni] = mfma16(afh[mi], bfl[ni], acc[mi][ni]);
      }
    __syncthreads();
  }

  #pragma unroll
  for (int ni = 0; ni < 4; ++ni) {
    const int n = bn*128 + nq + ni*16 + c;
    const float bv = bias[n];
    #pragma unroll
    for (int mi = 0; mi < 4; ++mi)
      #pragma unroll
      for (int r = 0; r < 4; ++r) {
        const int m = bm*128 + mq + mi*16 + 4*g + r;
        Out[(size_t)m*1024 + n] = acc[mi][ni][r] + bv;
      }
  }
}

// ---------------------------------------------------------------------------
// Flash attention: swapped-QK^T 32x32 MFMA, in-register softmax,
// LDS-staged K/V (double-buffered, shared by all 4 waves).
//  * K/V fragments are wave-invariant -> stage once per block: 4x less L2
//    traffic; reads come from LDS at the b128 floor (pitch 72 = 16B aligned).
//  * Issue-early/write-late staging (T14): global loads at loop top, ds_write
//    after compute, ONE barrier per tile (WAR-safe via double buffer).
//  * Tile = 64 kv, two 32-row chunks: chunk-1 QK^T (MFMA pipe) overlaps
//    chunk-0 exp/pack (VALU pipe).
// Grid: 1024 (XCD-chunked). 4 waves/block, wave = 32 q-rows x full D=64.
// ---------------------------------------------------------------------------
__global__ __launch_bounds__(256)
void attn_kernel(const bf16_t* __restrict__ Q, const bf16_t* __restrict__ K,
                 const bf16_t* __restrict__ Vt, const int* __restrict__ mask,
                 const float* __restrict__ rel_emb, float* __restrict__ ctx)
{
  __shared__ float relc[257];      // rel_emb[.,h] * log2e
  __shared__ float maskadd[2048];  // 0 or MASK_NEG (exp2 domain)
  __shared__ float linv[4][32];
  __shared__ __align__(16) bf16_t Ks[2][64][72];  // [buf][s'][d]
  __shared__ __align__(16) bf16_t Vs[2][64][72];  // [buf][d][s']

  const int tid  = threadIdx.x;
  const int w    = tid >> 6;
  const int lane = tid & 63;
  const int lq   = lane & 31;
  const int hi   = lane >> 5;

  const int bid = blockIdx.x;
  const int n   = (bid & 7) * 128 + (bid >> 3);   // XCD-chunked (1024 % 8 == 0)
  const int bh  = n >> 4;
  const int qblk= n & 15;
  const int b = bh >> 4, h = bh & 15;
  const int qw = qblk * 128 + w * 32;             // wave's q-base

  const bf16_t* Qb = Q  + ((size_t)bh * 2048) * 64;
  const bf16_t* Kb = K  + ((size_t)bh * 2048) * 64;
  const bf16_t* Vb = Vt + ((size_t)bh * 64) * 2048;

  // staging geometry: thread -> (row r, 16-elem quarter)
  const int sr  = tid >> 2;
  const int soff= (tid & 3) * 16;

  for (int i = tid; i < 257; i += 256)  relc[i] = rel_emb[i * 16 + h] * L2E;
  for (int i = tid; i < 2048; i += 256) maskadd[i] = mask[b * 2048 + i] ? 0.0f : MASK_NEG;

  // ---- prologue: stage tile 0 into buf 0 ----
  {
    const bf16_t* kp = Kb + (size_t)sr * 64 + soff;
    const bf16_t* vp = Vb + (size_t)sr * 2048 + soff;
    i32x4 k0 = *(const i32x4*)kp, k1 = *(const i32x4*)(kp + 8);
    i32x4 v0 = *(const i32x4*)vp, v1 = *(const i32x4*)(vp + 8);
    *(i32x4*)&Ks[0][sr][soff] = k0;  *(i32x4*)&Ks[0][sr][soff + 8] = k1;
    *(i32x4*)&Vs[0][sr][soff] = v0;  *(i32x4*)&Vs[0][sr][soff + 8] = v1;
  }
  __syncthreads();

  // Q as B-frag (col=q=lq, k-dim=d), hoisted
  bf16x8 qf[4];
  #pragma unroll
  for (int dc = 0; dc < 4; ++dc)
    qf[dc] = *(const bf16x8*)&Qb[(size_t)(qw + lq) * 64 + dc * 16 + 8 * hi];

  const float biasLo = relc[0];
  const float biasHi = relc[256];

  f32x16 O0 = {}, O1 = {};
  float lsum = 0.0f;

  // per-chunk softmax: sa (C[k][q]) -> p[16] (bf16-ready probabilities)
  auto SOFTMAX = [&](const f32x16& sa, int kvc, float* p) {
    const int d0 = kvc - qw;
    if (d0 >= 160 || d0 <= -160) {
      const float cb = (d0 >= 160) ? biasHi : biasLo;
      #pragma unroll
      for (int reg = 0; reg < 16; ++reg) {
        const int krow = (reg & 3) + 8 * (reg >> 2) + 4 * hi;
        p[reg] = exp2f(sa[reg] + (cb + maskadd[kvc + krow]));
      }
    } else {
      #pragma unroll
      for (int reg = 0; reg < 16; ++reg) {
        const int krow = (reg & 3) + 8 * (reg >> 2) + 4 * hi;
        int rr = kvc + krow - (qw + lq);
        rr = rr < -128 ? -128 : (rr > 128 ? 128 : rr);
        p[reg] = exp2f(sa[reg] + relc[rr + 128] + maskadd[kvc + krow]);
      }
    }
    #pragma unroll
    for (int reg = 0; reg < 16; ++reg) lsum += p[reg];
  };

  // pack p[16] -> two PV A-frags (k 0..15, 16..31 of the chunk)
  auto PACK = [&](const float* p, bf16x8& pa0, bf16x8& pa1) {
    unsigned w0 = cvtpk(p[0], p[1]), w1 = cvtpk(p[2], p[3]);
    unsigned w2 = cvtpk(p[4], p[5]), w3 = cvtpk(p[6], p[7]);
    asm volatile("v_permlane32_swap_b32 %0, %1" : "+v"(w0), "+v"(w2));
    asm volatile("v_permlane32_swap_b32 %0, %1" : "+v"(w1), "+v"(w3));
    i32x4 pw0 = { (int)w0, (int)w1, (int)w2, (int)w3 };
    pa0 = __builtin_bit_cast(bf16x8, pw0);
    unsigned w4 = cvtpk(p[8],  p[9]),  w5 = cvtpk(p[10], p[11]);
    unsigned w6 = cvtpk(p[12], p[13]), w7 = cvtpk(p[14], p[15]);
    asm volatile("v_permlane32_swap_b32 %0, %1" : "+v"(w4), "+v"(w6));
    asm volatile("v_permlane32_swap_b32 %0, %1" : "+v"(w5), "+v"(w7));
    i32x4 pw1 = { (int)w4, (int)w5, (int)w6, (int)w7 };
    pa1 = __builtin_bit_cast(bf16x8, pw1);
  };

  for (int t = 0; t < 32; ++t) {
    const int kv  = t * 64;
    const int cur = t & 1, nxt = cur ^ 1;
    const bool more = (t + 1 < 32);

    // ---- issue stage loads for tile t+1 (consumed after compute) ----
    i32x4 k0, k1, v0, v1;
    if (more) {
      const bf16_t* kp = Kb + (size_t)(kv + 64 + sr) * 64 + soff;
      const bf16_t* vp = Vb + (size_t)sr * 2048 + (kv + 64) + soff;
      k0 = *(const i32x4*)kp;  k1 = *(const i32x4*)(kp + 8);
      v0 = *(const i32x4*)vp;  v1 = *(const i32x4*)(vp + 8);
    }

    // ---- QK^T for both 32-row chunks (MFMA pipe fills while VALU packs) ----
    bf16x8 kf0[4], kf1[4];
    #pragma unroll
    for (int dc = 0; dc < 4; ++dc)
      kf0[dc] = *(const bf16x8*)&Ks[cur][lq][dc * 16 + 8 * hi];
    #pragma unroll
    for (int dc = 0; dc < 4; ++dc)
      kf1[dc] = *(const bf16x8*)&Ks[cur][32 + lq][dc * 16 + 8 * hi];

    f32x16 sa0 = {}, sa1 = {};
    __builtin_amdgcn_s_setprio(1);
    #pragma unroll
    for (int dc = 0; dc < 4; ++dc) sa0 = mfma32(kf0[dc], qf[dc], sa0);
    #pragma unroll
    for (int dc = 0; dc < 4; ++dc) sa1 = mfma32(kf1[dc], qf[dc], sa1);
    __builtin_amdgcn_s_setprio(0);

    // ---- V B-frags for this tile ----
    bf16x8 vf[4][2];
    #pragma unroll
    for (int kcg = 0; kcg < 4; ++kcg)
      #pragma unroll
      for (int db = 0; db < 2; ++db)
        vf[kcg][db] = *(const bf16x8*)&Vs[cur][db * 32 + lq][kcg * 16 + 8 * hi];

    // ---- chunk 0: softmax -> pack -> PV (overlaps chunk-1 work) ----
    float p[16];
    bf16x8 pa0, pa1;
    SOFTMAX(sa0, kv, p);
    PACK(p, pa0, pa1);
    __builtin_amdgcn_s_setprio(1);
    O0 = mfma32(pa0, vf[0][0], O0);
    O1 = mfma32(pa0, vf[0][1], O1);
    O0 = mfma32(pa1, vf[1][0], O0);
    O1 = mfma32(pa1, vf[1][1], O1);
    __builtin_amdgcn_s_setprio(0);

    // ---- chunk 1 ----
    SOFTMAX(sa1, kv + 32, p);
    PACK(p, pa0, pa1);
    __builtin_amdgcn_s_setprio(1);
    O0 = mfma32(pa0, vf[2][0], O0);
    O1 = mfma32(pa0, vf[2][1], O1);
    O0 = mfma32(pa1, vf[3][0], O0);
    O1 = mfma32(pa1, vf[3][1], O1);
    __builtin_amdgcn_s_setprio(0);

    // ---- write-late staging + single barrier (dbuf => WAR-safe) ----
    if (more) {
      *(i32x4*)&Ks[nxt][sr][soff] = k0;  *(i32x4*)&Ks[nxt][sr][soff + 8] = k1;
      *(i32x4*)&Vs[nxt][sr][soff] = v0;  *(i32x4*)&Vs[nxt][sr][soff + 8] = v1;
    }
    __syncthreads();
  }

  // ---- epilogue: combine half-wave sums; redistribute inv via tiny LDS ----
  lsum += __shfl_xor(lsum, 32);
  if (lane < 32) linv[w][lane] = (lsum > 0.0f) ? 1.0f / lsum : 0.0f;
  asm volatile("s_waitcnt lgkmcnt(0)" ::: "memory");
  __builtin_amdgcn_sched_barrier(0);

  #pragma unroll
  for (int reg = 0; reg < 16; ++reg) {
    const int qrow = (reg & 3) + 8 * (reg >> 2) + 4 * hi;
    const float iv = linv[w][qrow];
    const int s = qw + qrow;
    float* dst = &ctx[((size_t)(b * 2048 + s)) * 1024 + h * 64 + lq];
    dst[0]  = O0[reg] * iv;
    dst[32] = O1[reg] * iv;
  }
}

// ---------------------------------------------------------------------------
extern "C" void kernel_launch(void* const* d_in, const int* in_sizes, int n_in,
                              void* d_out, int out_size, void* d_ws, size_t ws_size,
                              hipStream_t stream)
{
  const float* q    = (const float*)d_in[0];
  const float* k    = (const float*)d_in[1];
  const float* v    = (const float*)d_in[2];
  const int*   mask = (const int*)  d_in[3];
  const float* Wq   = (const float*)d_in[4];
  const float* bq   = (const float*)d_in[5];
  const float* Wk   = (const float*)d_in[6];
  const float* bk   = (const float*)d_in[7];
  const float* Wv   = (const float*)d_in[8];
  const float* bv   = (const float*)d_in[9];
  const float* Wo   = (const float*)d_in[10];
  const float* bo   = (const float*)d_in[11];
  const float* rel  = (const float*)d_in[12];

  char* wsb = (char*)d_ws;
  bf16_t* Qw = (bf16_t*)(wsb);                        // 16 MB
  bf16_t* Kw = (bf16_t*)(wsb + ((size_t)16 << 20));   // 16 MB
  bf16_t* Vw = (bf16_t*)(wsb + ((size_t)32 << 20));   // 16 MB (transposed)
  float*  Cw = (float*) (wsb + ((size_t)48 << 20));   // 32 MB f32 ctx

  dim3 gg(8, 64), bb(256);
  proj_gemm<1><<<gg, bb, 0, stream>>>(q, Wq, bq, Qw, QSCALE);
  proj_gemm<1><<<gg, bb, 0, stream>>>(k, Wk, bk, Kw, 1.0f);
  proj_gemm<2><<<gg, bb, 0, stream>>>(v, Wv, bv, Vw, 1.0f);
  attn_kernel<<<dim3(1024), bb, 0, stream>>>(Qw, Kw, Vw, mask, rel, Cw);
  out_gemm<<<gg, bb, 0, stream>>>(Cw, Wo, bo, (float*)d_out);
}

// Round 6
// 314.033 us; speedup vs baseline: 2.4634x; 1.4583x over previous
//
#include <hip/hip_runtime.h>
#include <cstdint>
#include <cstddef>

typedef __bf16 bf16_t;
typedef __bf16 bf16x8 __attribute__((ext_vector_type(8)));
typedef float f32x4  __attribute__((ext_vector_type(4)));
typedef float f32x16 __attribute__((ext_vector_type(16)));
typedef int   i32x4  __attribute__((ext_vector_type(4)));

#define DEVI static __device__ __forceinline__

DEVI f32x4 mfma16(bf16x8 a, bf16x8 b, f32x4 c) {
  return __builtin_amdgcn_mfma_f32_16x16x32_bf16(a, b, c, 0, 0, 0);
}
DEVI f32x16 mfma32(bf16x8 a, bf16x8 b, f32x16 c) {
  return __builtin_amdgcn_mfma_f32_32x32x16_bf16(a, b, c, 0, 0, 0);
}
DEVI unsigned cvtpk(float lo, float hi) {
  unsigned d;
  asm("v_cvt_pk_bf16_f32 %0, %1, %2" : "=v"(d) : "v"(lo), "v"(hi));
  return d;
}
DEVI void gload_lds16(const bf16_t* g, bf16_t* l) {
  __builtin_amdgcn_global_load_lds(
      (const __attribute__((address_space(1))) void*)g,
      (__attribute__((address_space(3))) void*)l, 16, 0, 0);
}

#define L2E 1.44269504f
#define QSCALE (0.125f * L2E)      // folded into Q projection output
#define MASK_NEG (-60000.0f)       // exp2-domain; exp2(-60000+small) == 0

// ---------------------------------------------------------------------------
// Elementwise converters (memory-bound; vectorized 8 f32 -> 8 bf16 / thread)
// ---------------------------------------------------------------------------
__global__ __launch_bounds__(256)
void cvt_f32_bf16(const float* __restrict__ in, bf16_t* __restrict__ out, int n8)
{
  const int i = blockIdx.x * 256 + threadIdx.x;
  if (i >= n8) return;
  float4 a = ((const float4*)in)[2*i];
  float4 b = ((const float4*)in)[2*i + 1];
  bf16x8 o;
  o[0]=(bf16_t)a.x; o[1]=(bf16_t)a.y; o[2]=(bf16_t)a.z; o[3]=(bf16_t)a.w;
  o[4]=(bf16_t)b.x; o[5]=(bf16_t)b.y; o[6]=(bf16_t)b.z; o[7]=(bf16_t)b.w;
  ((bf16x8*)out)[i] = o;
}

__global__ __launch_bounds__(256)
void split_f32_bf16(const float* __restrict__ in, bf16_t* __restrict__ hi,
                    bf16_t* __restrict__ lo, int n8)
{
  const int i = blockIdx.x * 256 + threadIdx.x;
  if (i >= n8) return;
  float4 a = ((const float4*)in)[2*i];
  float4 b = ((const float4*)in)[2*i + 1];
  const float* f = (const float*)&a;
  bf16x8 oh, ol;
  #pragma unroll
  for (int j = 0; j < 4; ++j) { bf16_t h=(bf16_t)f[j]; oh[j]=h; ol[j]=(bf16_t)(f[j]-(float)h); }
  const float* f2 = (const float*)&b;
  #pragma unroll
  for (int j = 0; j < 4; ++j) { bf16_t h=(bf16_t)f2[j]; oh[4+j]=h; ol[4+j]=(bf16_t)(f2[j]-(float)h); }
  ((bf16x8*)hi)[i] = oh;
  ((bf16x8*)lo)[i] = ol;
}

// ---------------------------------------------------------------------------
// proj_gemm97: C = (A[8192,1024](bf16) @ W^T(bf16) + bias) * oscale, out bf16.
// m97 structure: 128x128 tile, BK=64, global_load_lds width=16 into LINEAR
// LDS [128][64], 2 barriers/K-step, 4 waves, mfma 16x16x32.
// OMODE 1: out[b,h,s,d];  OMODE 2: out[b,h,d,s] (transposed V)
// ---------------------------------------------------------------------------
template<int OMODE>
__global__ __launch_bounds__(256)
void proj_gemm97(const bf16_t* __restrict__ A, const bf16_t* __restrict__ W,
                 const float* __restrict__ bias, bf16_t* __restrict__ Out,
                 float oscale)
{
  __shared__ __align__(16) bf16_t As[128 * 64];
  __shared__ __align__(16) bf16_t Bs[128 * 64];
  const int tid  = threadIdx.x;
  const int lane = tid & 63;
  const int w    = tid >> 6;
  const int g = lane >> 4, c = lane & 15;
  const int mq = (w >> 1) * 64, nq = (w & 1) * 64;
  const int bm = blockIdx.y, bn = blockIdx.x;

  // staging: instruction inst covers rows inst*8..inst*8+7, lane l -> row
  // inst*8 + (l>>3), k-col (l&7)*8  == LDS linear offset inst*1024B + l*16B.
  const int rsub = lane >> 3;
  const int kc8  = (lane & 7) * 8;

  f32x4 acc[4][4] = {};

  for (int kt = 0; kt < 1024; kt += 64) {
    #pragma unroll
    for (int i = 0; i < 4; ++i) {
      const int inst = w * 4 + i;
      const int row  = inst * 8 + rsub;
      gload_lds16(A + (size_t)(bm*128 + row)*1024 + kt + kc8, &As[inst*512]);
      gload_lds16(W + (size_t)(bn*128 + row)*1024 + kt + kc8, &Bs[inst*512]);
    }
    __syncthreads();   // compiler drains vmcnt before s_barrier
    #pragma unroll
    for (int kk = 0; kk < 64; kk += 32) {
      bf16x8 af[4], bfv[4];
      #pragma unroll
      for (int i = 0; i < 4; ++i) {
        af[i]  = *(const bf16x8*)&As[(mq + i*16 + c)*64 + kk + 8*g];
        bfv[i] = *(const bf16x8*)&Bs[(nq + i*16 + c)*64 + kk + 8*g];
      }
      #pragma unroll
      for (int mi = 0; mi < 4; ++mi)
        #pragma unroll
        for (int ni = 0; ni < 4; ++ni)
          acc[mi][ni] = mfma16(af[mi], bfv[ni], acc[mi][ni]);
    }
    __syncthreads();   // WAR: next staging overwrites
  }

  #pragma unroll
  for (int ni = 0; ni < 4; ++ni) {
    const int n = bn*128 + nq + ni*16 + c;
    const float bv = bias[n];
    const int h = n >> 6, d = n & 63;
    #pragma unroll
    for (int mi = 0; mi < 4; ++mi) {
      #pragma unroll
      for (int r = 0; r < 4; ++r) {
        const int m = bm*128 + mq + mi*16 + 4*g + r;
        const float v = (acc[mi][ni][r] + bv) * oscale;
        const int bb = m >> 11, s = m & 2047;
        if (OMODE == 1)
          Out[(((size_t)(bb*16 + h))*2048 + s)*64 + d] = (bf16_t)v;
        else
          Out[(((size_t)(bb*16 + h))*64 + d)*2048 + s] = (bf16_t)v;
      }
    }
  }
}

// ---------------------------------------------------------------------------
// out_gemm97: split-precision GEMM from pure-bf16 inputs:
//   Out = (Ah+Al) @ (Bh+Bl)^T + bias ~= Ah Bh + Al Bh + Ah Bl   (f32-class)
// m97 staging for all 4 tiles (64 KB LDS, 2 blocks/CU = grid exactly).
// ---------------------------------------------------------------------------
__global__ __launch_bounds__(256)
void out_gemm97(const bf16_t* __restrict__ Ahg, const bf16_t* __restrict__ Alg,
                const bf16_t* __restrict__ Bhg, const bf16_t* __restrict__ Blg,
                const float* __restrict__ bias, float* __restrict__ Out)
{
  __shared__ __align__(16) bf16_t Ahs[128 * 64];
  __shared__ __align__(16) bf16_t Als[128 * 64];
  __shared__ __align__(16) bf16_t Bhs[128 * 64];
  __shared__ __align__(16) bf16_t Bls[128 * 64];
  const int tid  = threadIdx.x;
  const int lane = tid & 63;
  const int w    = tid >> 6;
  const int g = lane >> 4, c = lane & 15;
  const int mq = (w >> 1) * 64, nq = (w & 1) * 64;
  const int bm = blockIdx.y, bn = blockIdx.x;

  const int rsub = lane >> 3;
  const int kc8  = (lane & 7) * 8;

  f32x4 acc[4][4] = {};

  for (int kt = 0; kt < 1024; kt += 64) {
    #pragma unroll
    for (int i = 0; i < 4; ++i) {
      const int inst = w * 4 + i;
      const int row  = inst * 8 + rsub;
      const size_t ga = (size_t)(bm*128 + row)*1024 + kt + kc8;
      const size_t gb = (size_t)(bn*128 + row)*1024 + kt + kc8;
      gload_lds16(Ahg + ga, &Ahs[inst*512]);
      gload_lds16(Alg + ga, &Als[inst*512]);
      gload_lds16(Bhg + gb, &Bhs[inst*512]);
      gload_lds16(Blg + gb, &Bls[inst*512]);
    }
    __syncthreads();
    #pragma unroll
    for (int kk = 0; kk < 64; kk += 32) {
      bf16x8 afh[4], afl[4], bfh[4], bfl[4];
      #pragma unroll
      for (int i = 0; i < 4; ++i) {
        const int ar = (mq + i*16 + c)*64 + kk + 8*g;
        const int br = (nq + i*16 + c)*64 + kk + 8*g;
        afh[i] = *(const bf16x8*)&Ahs[ar];
        afl[i] = *(const bf16x8*)&Als[ar];
        bfh[i] = *(const bf16x8*)&Bhs[br];
        bfl[i] = *(const bf16x8*)&Bls[br];
      }
      #pragma unroll
      for (int mi = 0; mi < 4; ++mi)
        #pragma unroll
        for (int ni = 0; ni < 4; ++ni) {
          acc[mi][ni] = mfma16(afh[mi], bfh[ni], acc[mi][ni]);
          acc[mi][ni] = mfma16(afl[mi], bfh[ni], acc[mi][ni]);
          acc[mi][ni] = mfma16(afh[mi], bfl[ni], acc[mi][ni]);
        }
    }
    __syncthreads();
  }

  #pragma unroll
  for (int ni = 0; ni < 4; ++ni) {
    const int n = bn*128 + nq + ni*16 + c;
    const float bv = bias[n];
    #pragma unroll
    for (int mi = 0; mi < 4; ++mi)
      #pragma unroll
      for (int r = 0; r < 4; ++r) {
        const int m = bm*128 + mq + mi*16 + 4*g + r;
        Out[(size_t)m*1024 + n] = acc[mi][ni][r] + bv;
      }
  }
}

// ---------------------------------------------------------------------------
// Flash attention: swapped-QK^T 32x32 MFMA, in-register softmax,
// LDS-staged K/V (double-buffered). Epilogue writes split-bf16 ctx (Ch, Cl).
// Grid: 1024 (XCD-chunked). 4 waves/block, wave = 32 q-rows x full D=64.
// ---------------------------------------------------------------------------
__global__ __launch_bounds__(256)
void attn_kernel(const bf16_t* __restrict__ Q, const bf16_t* __restrict__ K,
                 const bf16_t* __restrict__ Vt, const int* __restrict__ mask,
                 const float* __restrict__ rel_emb,
                 bf16_t* __restrict__ Ch, bf16_t* __restrict__ Cl)
{
  __shared__ float relc[257];      // rel_emb[.,h] * log2e
  __shared__ float maskadd[2048];  // 0 or MASK_NEG (exp2 domain)
  __shared__ float linv[4][32];
  __shared__ __align__(16) bf16_t Ks[2][64][72];  // [buf][s'][d]
  __shared__ __align__(16) bf16_t Vs[2][64][72];  // [buf][d][s']

  const int tid  = threadIdx.x;
  const int w    = tid >> 6;
  const int lane = tid & 63;
  const int lq   = lane & 31;
  const int hi   = lane >> 5;

  const int bid = blockIdx.x;
  const int n   = (bid & 7) * 128 + (bid >> 3);   // XCD-chunked (1024 % 8 == 0)
  const int bh  = n >> 4;
  const int qblk= n & 15;
  const int b = bh >> 4, h = bh & 15;
  const int qw = qblk * 128 + w * 32;             // wave's q-base

  const bf16_t* Qb = Q  + ((size_t)bh * 2048) * 64;
  const bf16_t* Kb = K  + ((size_t)bh * 2048) * 64;
  const bf16_t* Vb = Vt + ((size_t)bh * 64) * 2048;

  const int sr  = tid >> 2;
  const int soff= (tid & 3) * 16;

  for (int i = tid; i < 257; i += 256)  relc[i] = rel_emb[i * 16 + h] * L2E;
  for (int i = tid; i < 2048; i += 256) maskadd[i] = mask[b * 2048 + i] ? 0.0f : MASK_NEG;

  // ---- prologue: stage tile 0 into buf 0 ----
  {
    const bf16_t* kp = Kb + (size_t)sr * 64 + soff;
    const bf16_t* vp = Vb + (size_t)sr * 2048 + soff;
    i32x4 k0 = *(const i32x4*)kp, k1 = *(const i32x4*)(kp + 8);
    i32x4 v0 = *(const i32x4*)vp, v1 = *(const i32x4*)(vp + 8);
    *(i32x4*)&Ks[0][sr][soff] = k0;  *(i32x4*)&Ks[0][sr][soff + 8] = k1;
    *(i32x4*)&Vs[0][sr][soff] = v0;  *(i32x4*)&Vs[0][sr][soff + 8] = v1;
  }
  __syncthreads();

  bf16x8 qf[4];
  #pragma unroll
  for (int dc = 0; dc < 4; ++dc)
    qf[dc] = *(const bf16x8*)&Qb[(size_t)(qw + lq) * 64 + dc * 16 + 8 * hi];

  const float biasLo = relc[0];
  const float biasHi = relc[256];

  f32x16 O0 = {}, O1 = {};
  float lsum = 0.0f;

  auto SOFTMAX = [&](const f32x16& sa, int kvc, float* p) {
    const int d0 = kvc - qw;
    if (d0 >= 160 || d0 <= -160) {
      const float cb = (d0 >= 160) ? biasHi : biasLo;
      #pragma unroll
      for (int reg = 0; reg < 16; ++reg) {
        const int krow = (reg & 3) + 8 * (reg >> 2) + 4 * hi;
        p[reg] = exp2f(sa[reg] + (cb + maskadd[kvc + krow]));
      }
    } else {
      #pragma unroll
      for (int reg = 0; reg < 16; ++reg) {
        const int krow = (reg & 3) + 8 * (reg >> 2) + 4 * hi;
        int rr = kvc + krow - (qw + lq);
        rr = rr < -128 ? -128 : (rr > 128 ? 128 : rr);
        p[reg] = exp2f(sa[reg] + relc[rr + 128] + maskadd[kvc + krow]);
      }
    }
    #pragma unroll
    for (int reg = 0; reg < 16; ++reg) lsum += p[reg];
  };

  auto PACK = [&](const float* p, bf16x8& pa0, bf16x8& pa1) {
    unsigned w0 = cvtpk(p[0], p[1]), w1 = cvtpk(p[2], p[3]);
    unsigned w2 = cvtpk(p[4], p[5]), w3 = cvtpk(p[6], p[7]);
    asm volatile("v_permlane32_swap_b32 %0, %1" : "+v"(w0), "+v"(w2));
    asm volatile("v_permlane32_swap_b32 %0, %1" : "+v"(w1), "+v"(w3));
    i32x4 pw0 = { (int)w0, (int)w1, (int)w2, (int)w3 };
    pa0 = __builtin_bit_cast(bf16x8, pw0);
    unsigned w4 = cvtpk(p[8],  p[9]),  w5 = cvtpk(p[10], p[11]);
    unsigned w6 = cvtpk(p[12], p[13]), w7 = cvtpk(p[14], p[15]);
    asm volatile("v_permlane32_swap_b32 %0, %1" : "+v"(w4), "+v"(w6));
    asm volatile("v_permlane32_swap_b32 %0, %1" : "+v"(w5), "+v"(w7));
    i32x4 pw1 = { (int)w4, (int)w5, (int)w6, (int)w7 };
    pa1 = __builtin_bit_cast(bf16x8, pw1);
  };

  for (int t = 0; t < 32; ++t) {
    const int kv  = t * 64;
    const int cur = t & 1, nxt = cur ^ 1;
    const bool more = (t + 1 < 32);

    i32x4 k0, k1, v0, v1;
    if (more) {
      const bf16_t* kp = Kb + (size_t)(kv + 64 + sr) * 64 + soff;
      const bf16_t* vp = Vb + (size_t)sr * 2048 + (kv + 64) + soff;
      k0 = *(const i32x4*)kp;  k1 = *(const i32x4*)(kp + 8);
      v0 = *(const i32x4*)vp;  v1 = *(const i32x4*)(vp + 8);
    }

    bf16x8 kf0[4], kf1[4];
    #pragma unroll
    for (int dc = 0; dc < 4; ++dc)
      kf0[dc] = *(const bf16x8*)&Ks[cur][lq][dc * 16 + 8 * hi];
    #pragma unroll
    for (int dc = 0; dc < 4; ++dc)
      kf1[dc] = *(const bf16x8*)&Ks[cur][32 + lq][dc * 16 + 8 * hi];

    f32x16 sa0 = {}, sa1 = {};
    __builtin_amdgcn_s_setprio(1);
    #pragma unroll
    for (int dc = 0; dc < 4; ++dc) sa0 = mfma32(kf0[dc], qf[dc], sa0);
    #pragma unroll
    for (int dc = 0; dc < 4; ++dc) sa1 = mfma32(kf1[dc], qf[dc], sa1);
    __builtin_amdgcn_s_setprio(0);

    bf16x8 vf[4][2];
    #pragma unroll
    for (int kcg = 0; kcg < 4; ++kcg)
      #pragma unroll
      for (int db = 0; db < 2; ++db)
        vf[kcg][db] = *(const bf16x8*)&Vs[cur][db * 32 + lq][kcg * 16 + 8 * hi];

    float p[16];
    bf16x8 pa0, pa1;
    SOFTMAX(sa0, kv, p);
    PACK(p, pa0, pa1);
    __builtin_amdgcn_s_setprio(1);
    O0 = mfma32(pa0, vf[0][0], O0);
    O1 = mfma32(pa0, vf[0][1], O1);
    O0 = mfma32(pa1, vf[1][0], O0);
    O1 = mfma32(pa1, vf[1][1], O1);
    __builtin_amdgcn_s_setprio(0);

    SOFTMAX(sa1, kv + 32, p);
    PACK(p, pa0, pa1);
    __builtin_amdgcn_s_setprio(1);
    O0 = mfma32(pa0, vf[2][0], O0);
    O1 = mfma32(pa0, vf[2][1], O1);
    O0 = mfma32(pa1, vf[3][0], O0);
    O1 = mfma32(pa1, vf[3][1], O1);
    __builtin_amdgcn_s_setprio(0);

    if (more) {
      *(i32x4*)&Ks[nxt][sr][soff] = k0;  *(i32x4*)&Ks[nxt][sr][soff + 8] = k1;
      *(i32x4*)&Vs[nxt][sr][soff] = v0;  *(i32x4*)&Vs[nxt][sr][soff + 8] = v1;
    }
    __syncthreads();
  }

  lsum += __shfl_xor(lsum, 32);
  if (lane < 32) linv[w][lane] = (lsum > 0.0f) ? 1.0f / lsum : 0.0f;
  asm volatile("s_waitcnt lgkmcnt(0)" ::: "memory");
  __builtin_amdgcn_sched_barrier(0);

  #pragma unroll
  for (int reg = 0; reg < 16; ++reg) {
    const int qrow = (reg & 3) + 8 * (reg >> 2) + 4 * hi;
    const float iv = linv[w][qrow];
    const int s = qw + qrow;
    const size_t base = ((size_t)(b * 2048 + s)) * 1024 + h * 64 + lq;
    const float o0 = O0[reg] * iv, o1 = O1[reg] * iv;
    const bf16_t h0 = (bf16_t)o0, h1 = (bf16_t)o1;
    Ch[base]      = h0;  Cl[base]      = (bf16_t)(o0 - (float)h0);
    Ch[base + 32] = h1;  Cl[base + 32] = (bf16_t)(o1 - (float)h1);
  }
}

// ---------------------------------------------------------------------------
extern "C" void kernel_launch(void* const* d_in, const int* in_sizes, int n_in,
                              void* d_out, int out_size, void* d_ws, size_t ws_size,
                              hipStream_t stream)
{
  const float* q    = (const float*)d_in[0];
  const float* k    = (const float*)d_in[1];
  const float* v    = (const float*)d_in[2];
  const int*   mask = (const int*)  d_in[3];
  const float* Wq   = (const float*)d_in[4];
  const float* bq   = (const float*)d_in[5];
  const float* Wk   = (const float*)d_in[6];
  const float* bk   = (const float*)d_in[7];
  const float* Wv   = (const float*)d_in[8];
  const float* bv   = (const float*)d_in[9];
  const float* Wo   = (const float*)d_in[10];
  const float* bo   = (const float*)d_in[11];
  const float* rel  = (const float*)d_in[12];

  char* wsb = (char*)d_ws;
  bf16_t* Qw  = (bf16_t*)(wsb);                         // 16 MiB proj-Q out
  bf16_t* Kw  = (bf16_t*)(wsb + ((size_t) 16 << 20));   // 16 MiB proj-K out
  bf16_t* Vw  = (bf16_t*)(wsb + ((size_t) 32 << 20));   // 16 MiB proj-V out (T)
  bf16_t* Qc  = (bf16_t*)(wsb + ((size_t) 48 << 20));   // query bf16 / later Ch
  bf16_t* Kc  = (bf16_t*)(wsb + ((size_t) 64 << 20));   // key   bf16 / later Cl
  bf16_t* Vc  = (bf16_t*)(wsb + ((size_t) 80 << 20));   // value bf16
  bf16_t* Wqc = (bf16_t*)(wsb + ((size_t) 96 << 20));   // 2 MiB
  bf16_t* Wkc = (bf16_t*)(wsb + ((size_t) 98 << 20));
  bf16_t* Wvc = (bf16_t*)(wsb + ((size_t)100 << 20));
  bf16_t* Woh = (bf16_t*)(wsb + ((size_t)102 << 20));
  bf16_t* Wol = (bf16_t*)(wsb + ((size_t)104 << 20));
  bf16_t* Chp = Qc;   // ctx split-high, aliases consumed Qc
  bf16_t* Clp = Kc;   // ctx split-low,  aliases consumed Kc

  const int n8t = 8192 * 1024 / 8;   // 1,048,576
  const int n8w = 1024 * 1024 / 8;   // 131,072
  dim3 bb(256);

  cvt_f32_bf16<<<dim3(4096), bb, 0, stream>>>(q, Qc, n8t);
  cvt_f32_bf16<<<dim3(4096), bb, 0, stream>>>(k, Kc, n8t);
  cvt_f32_bf16<<<dim3(4096), bb, 0, stream>>>(v, Vc, n8t);
  cvt_f32_bf16<<<dim3(512),  bb, 0, stream>>>(Wq, Wqc, n8w);
  cvt_f32_bf16<<<dim3(512),  bb, 0, stream>>>(Wk, Wkc, n8w);
  cvt_f32_bf16<<<dim3(512),  bb, 0, stream>>>(Wv, Wvc, n8w);
  split_f32_bf16<<<dim3(512), bb, 0, stream>>>(Wo, Woh, Wol, n8w);

  dim3 gg(8, 64);
  proj_gemm97<1><<<gg, bb, 0, stream>>>(Qc, Wqc, bq, Qw, QSCALE);
  proj_gemm97<1><<<gg, bb, 0, stream>>>(Kc, Wkc, bk, Kw, 1.0f);
  proj_gemm97<2><<<gg, bb, 0, stream>>>(Vc, Wvc, bv, Vw, 1.0f);
  attn_kernel<<<dim3(1024), bb, 0, stream>>>(Qw, Kw, Vw, mask, rel, Chp, Clp);
  out_gemm97<<<gg, bb, 0, stream>>>(Chp, Clp, Woh, Wol, bo, (float*)d_out);
}